// Round 13
// baseline (2264.811 us; speedup 1.0000x reference)
//
#include <hip/hip_runtime.h>
#include <hip/hip_bf16.h>

// SRNN: x_{t+1} = x + DT*(-x + J@rates + inp), rates = 0.5*(1+tanh(x)),
// out[p,t] = (w_out @ rates_t)[p] / N.
//
// v13 = v12 dense-MFMA step re-occupied: 1024 thr (16 waves = 4/SIMD, was
// 2/SIMD), BK=256 -> 8 phases (was 16 barriers), 2-buf LDS (48KB x 2).
//  - v12 analysis: L2 floor 2.9us of 7.2us kernel; ~4us = exposed latency
//    at 2 waves/SIMD across 16 vmcnt+barrier drains. 4 waves/SIMD + half
//    the barriers attacks exactly that term. Traffic unchanged (96MB/step).
//  - wave = (m-half s, k-eighth kq): 2 MFMA 32x32x16 per phase, f32x16 acc,
//    8-way kq reduce through LDS planes (v12-verified plane/C-layout).
//  - 2-buf protocol (no 4-buf WAR distance): vmcnt(0) -> s_barrier ->
//    issue stage(ph+1) -> sched_barrier -> ds_read+MFMA. Issue-after-barrier
//    makes buffer overwrite safe (all readers past barrier).
//  - kperm16 J layout, XOR-16 chunk swizzle both sides, XCD-contiguous
//    m-panels, fused epilogue + rates_T LDS transpose: v12-verified.
// [history: sparse plateau 2114-2360; coop/persistent dead ends; v9 2119
//  (1 wave/SIMD); v10 1972 (2/SIMD, 16x16x32); v12 1931 (32x32x16).]

#define NN 2048
#define PP 256
#define DT_C 0.1f
#define ON_TIME_C 10

typedef __attribute__((ext_vector_type(8)))  short bf16x8;
typedef __attribute__((ext_vector_type(16))) float f32x16;

__device__ __forceinline__ unsigned short bf16rne(float f) {
    unsigned b = __float_as_uint(f);
    return (unsigned short)((b + 0x7FFFu + ((b >> 16) & 1u)) >> 16);
}
// 32x32x16 fragment permutation within a 16-k group (v12-verified).
__device__ __forceinline__ int kperm16(int s) {
    return (s & 3) + (((s >> 2) & 1) << 3) + ((s >> 3) << 2);
}

// ---- J f32 [N][N] -> bf16 [N][N], k-permuted per 16-group ----
__global__ void convert_J_kernel(const float* __restrict__ J,
                                 unsigned short* __restrict__ Jp) {
    int i = blockIdx.x * blockDim.x + threadIdx.x;   // grid covers NN*NN
    int row = i >> 11, k = i & 2047;
    Jp[((size_t)row << 11) + (k & ~15) + kperm16(k & 15)] = bf16rne(J[i]);
}

// ---- x = 0, rates_T = bf16(0.5) (perm-invariant), out = 0 ----
__global__ void init_kernel(float* __restrict__ x,
                            unsigned short* __restrict__ rT,
                            float* __restrict__ out, int nout) {
    int i = blockIdx.x * blockDim.x + threadIdx.x;   // grid covers NN*PP
    x[i] = 0.0f;
    rT[i] = 0x3F00;
    if (i < nout) out[i] = 0.0f;
}

#define AS1 __attribute__((address_space(1)))
#define AS3 __attribute__((address_space(3)))
#define GLOAD16(g, l) \
    __builtin_amdgcn_global_load_lds((const AS1 void*)(g), (AS3 void*)(l), 16, 0, 0)

// ---- One time step. grid 256 (1/CU), 1024 thr (16 waves, 4/SIMD).
// BM=64 BN=32 BK=256, 8 phases, 2-buf LDS. ----
__global__ __launch_bounds__(1024, 1) void gemm_step_kernel(
    const unsigned short* __restrict__ Jp,    // [N][N] bf16 kperm16'd
    const unsigned short* __restrict__ rin,   // rates_T [P][N] bf16 kperm16'd
    unsigned short* __restrict__ rout,        // rates_T [P][N]
    float* __restrict__ x, const float* __restrict__ patterns,
    const float* __restrict__ w_out, float* __restrict__ out,
    int t, int T, int with_input) {

    __shared__ char smem[98304];              // 2 bufs x (A 32KB + B 16KB)

    const int tid  = threadIdx.x;
    const int wv   = tid >> 6;                // wave 0..15
    const int lane = tid & 63;
    const int s    = wv >> 3;                 // m-half (32 rows)
    const int kq   = wv & 7;                  // k-eighth role
    const int h    = lane >> 5;               // chunk-half within k16 frag

    // XCD-contiguous swizzle: XCD owns 4 contiguous m-panels.
    const int bid   = (blockIdx.x & 7) * 32 + (blockIdx.x >> 3);
    const int mbase = (bid >> 3) * 64;
    const int nbase = (bid & 7) * 32;

    // ---- staging: 3 loads/thread/phase. Rows are 512B (32 chunks of 16B).
    // set0: A rows 0..31, set1: A rows 32..63, set2: B rows 0..31.
    // dest check: ra*512 + p*16 == 1024*wv + lane*16 (wave-uniform base). ----
    const int p   = tid & 31;                 // chunk
    const int ra0 = tid >> 5;                 // 0..31
    const int ra1 = 32 + ra0;
    const char* gA0 = (const char*)Jp  + (((size_t)(mbase + ra0)) << 12)
                      + ((p ^ (ra0 & 15)) << 4);
    const char* gA1 = (const char*)Jp  + (((size_t)(mbase + ra1)) << 12)
                      + ((p ^ (ra1 & 15)) << 4);
    const char* gB  = (const char*)rin + (((size_t)(nbase + ra0)) << 12)
                      + ((p ^ (ra0 & 15)) << 4);
    const int ldsA0 = 1024 * wv;              // wave-uniform dest bases
    const int ldsA1 = 16384 + 1024 * wv;
    const int ldsB  = 32768 + 1024 * wv;

    // ---- fragment read rows ----
    const int rA  = 32 * s + (lane & 31);     // A row (local, 0..63)
    const int rBn = lane & 31;                // B row (local n, 0..31)

    f32x16 acc = {};

    // prologue: stage phase 0 -> buf 0
    GLOAD16(gA0, smem + ldsA0);
    GLOAD16(gA1, smem + ldsA1);
    GLOAD16(gB,  smem + ldsB);

    // ---- K-loop: 8 phases of BK=256; wave computes k16 slices 2kq,2kq+1 ----
    #pragma unroll
    for (int ph = 0; ph < 8; ++ph) {
        asm volatile("s_waitcnt vmcnt(0)" ::: "memory");  // my stage(ph) done
        __builtin_amdgcn_s_barrier();         // all waves' stage(ph) visible;
                                              // all reads of buf^1 finished
        if (ph < 7) {                         // issue stage(ph+1) -> buf^1
            const int bo = ((ph + 1) & 1) * 49152;
            GLOAD16(gA0 + (ph + 1) * 512, smem + bo + ldsA0);
            GLOAD16(gA1 + (ph + 1) * 512, smem + bo + ldsA1);
            GLOAD16(gB  + (ph + 1) * 512, smem + bo + ldsB);
        }
        __builtin_amdgcn_sched_barrier(0);    // keep reads below barrier/issue

        const int bb = (ph & 1) * 49152;
        #pragma unroll
        for (int sl = 0; sl < 2; ++sl) {
            const int c = (kq * 2 + sl) * 2 + h;   // 16B chunk in 512B row
            bf16x8 a = *(const bf16x8*)(smem + bb + rA * 512
                                        + ((c ^ (rA & 15)) << 4));
            bf16x8 b = *(const bf16x8*)(smem + bb + 32768 + rBn * 512
                                        + ((c ^ (rBn & 15)) << 4));
            acc = __builtin_amdgcn_mfma_f32_32x32x16_bf16(a, b, acc, 0, 0, 0);
        }
    }

    __syncthreads();                          // all reads done; reuse smem

    // ---- write kq-partials: plane (s*8+kq), [32 row][32 col] f32 = 64KB ----
    {
        float* pf = (float*)smem;
        const int plane = (s * 8 + kq) * 1024;
        #pragma unroll
        for (int reg = 0; reg < 16; ++reg) {
            int row = (reg & 3) + 8 * (reg >> 2) + 4 * h;   // v12-verified
            pf[plane + row * 32 + (lane & 31)] = acc[reg];
        }
    }
    __syncthreads();

    // ---- reduce 8 kq-planes + epilogue. thread -> (mloc, 2 cols) ----
    {
        const int mloc = tid >> 4;            // 0..63
        const int c2   = (tid & 15) * 2;      // 0..30
        const int s2   = mloc >> 5;
        const float* pf = (const float*)smem;
        float2 sum = make_float2(0.f, 0.f);
        #pragma unroll
        for (int q = 0; q < 8; ++q) {         // kq ascending: deterministic
            float2 v = *(const float2*)(pf + (s2 * 8 + q) * 1024
                                        + (mloc & 31) * 32 + c2);
            sum.x += v.x; sum.y += v.y;
        }

        const int m  = mbase + mloc;
        const int n0 = nbase + c2;
        size_t xo = ((size_t)m << 8) + n0;
        float2 xv = *(const float2*)(x + xo);
        float2 pv = make_float2(0.f, 0.f);
        if (with_input) pv = *(const float2*)(patterns + xo);
        float wsc = (w_out[m] != 0.0f) ? (1.0f / (float)NN) : 0.0f;

        float xn0 = xv.x + DT_C * (sum.x + pv.x - xv.x);
        float xn1 = xv.y + DT_C * (sum.y + pv.y - xv.y);
        *(float2*)(x + xo) = make_float2(xn0, xn1);
        float r0f = 0.5f * (1.0f + tanhf(xn0));
        float r1f = 0.5f * (1.0f + tanhf(xn1));
        if (wsc != 0.0f) {
            atomicAdd(&out[(size_t)n0 * T + t],       r0f * wsc);
            atomicAdd(&out[(size_t)(n0 + 1) * T + t], r1f * wsc);
        }
        // slab [32 n][64 m] bf16 at 65536, XOR-swizzled chunks (v12 formulas)
        const int pos = (mloc & ~15) + kperm16(mloc & 15);
        int b0 = 65536 + c2 * 128       + (((pos >> 3) ^ (c2 & 7)) << 4)       + (pos & 7) * 2;
        int b1 = 65536 + (c2 + 1) * 128 + (((pos >> 3) ^ ((c2 + 1) & 7)) << 4) + (pos & 7) * 2;
        *(unsigned short*)(smem + b0) = bf16rne(r0f);
        *(unsigned short*)(smem + b1) = bf16rne(r1f);
    }
    __syncthreads();
    if (tid < 256) {   // linear write-out of the block's [32 n][64 m] slab
        int nl = tid >> 3, pc = tid & 7;
        uint4 v = *(const uint4*)(smem + 65536 + nl * 128 + ((pc ^ (nl & 7)) << 4));
        *(uint4*)((char*)rout + (((size_t)(nbase + nl)) << 12) + mbase * 2 + pc * 16) = v;
    }
}

extern "C" void kernel_launch(void* const* d_in, const int* in_sizes, int n_in,
                              void* d_out, int out_size, void* d_ws, size_t ws_size,
                              hipStream_t stream) {
    const float* patterns = (const float*)d_in[0];   // [N, P]
    const float* J        = (const float*)d_in[1];   // [N, N]
    const float* w_out    = (const float*)d_in[2];   // [N]
    float* out            = (float*)d_out;           // [P, T]

    int T = out_size / PP;                           // 200

    size_t off = 0;
    auto alloc = [&](size_t bytes) {
        void* p = (char*)d_ws + off;
        off += (bytes + 255) & ~(size_t)255;
        return p;
    };
    unsigned short* Jp = (unsigned short*)alloc((size_t)NN * NN * 2);  // 8MB
    unsigned short* r0 = (unsigned short*)alloc((size_t)PP * NN * 2);  // 1MB
    unsigned short* r1 = (unsigned short*)alloc((size_t)PP * NN * 2);  // 1MB
    float*          x  = (float*)         alloc((size_t)NN * PP * 4);  // 2MB
    (void)ws_size; (void)n_in; (void)in_sizes;

    convert_J_kernel<<<(NN * NN) / 256, 256, 0, stream>>>(J, Jp);
    init_kernel<<<(NN * PP) / 256, 256, 0, stream>>>(x, r0, out, PP * T);

    for (int t = 0; t < T; ++t) {
        const unsigned short* rin = (t & 1) ? r1 : r0;
        unsigned short*      rout = (t & 1) ? r0 : r1;
        gemm_step_kernel<<<256, 1024, 0, stream>>>(Jp, rin, rout, x, patterns,
                                                   w_out, out, t, T,
                                                   (t < ON_TIME_C) ? 1 : 0);
    }
}

// Round 14
// 1982.130 us; speedup vs baseline: 1.1426x; 1.1426x over previous
//
#include <hip/hip_runtime.h>
#include <hip/hip_bf16.h>

// SRNN: x_{t+1} = x + DT*(-x + J@rates + inp), rates = 0.5*(1+tanh(x)),
// out[p,t] = (w_out @ rates_t)[p] / N.
//
// v14 = v12's EXACT 4-buf counted-vmcnt protocol (BK=128, 16 phases, 256B
// rows, issue-stage(ph+2)-then-wait, XOR-16 chunk swizzle) at DOUBLE the
// occupancy: 1024 thr = 16 waves = 4/SIMD (v12 was 2/SIMD).
//  - v13 post-mortem: its regression was the 2-buf vmcnt(0)-per-phase drain
//    (T4 anti-pattern), not the occupancy. This round changes ONLY occupancy.
//  - wave = (m-half s, k-eighth kq): 1 MFMA 32x32x16 + 2 ds_read per phase.
//  - staging: every wave stages its A chunk (4 rows = 1KB); waves 8-15 also
//    stage B. Per-wave counted vmcnt: w<8 vmcnt(2/1/0), w>=8 vmcnt(4/2/0).
//  - 4-buf WAR safety as v12: stage(ph+2) hits buf[(ph-2)&3], readers done.
//  - epilogue: v13's verified 16-plane kq-reduce + fused x/tanh/readout +
//    rates_T LDS transpose (identical absmax in v13).
// [history: sparse plateau 2114-2360; coop/persistent dead ends; v9 2119;
//  v10 1972 (2/SIMD 16x16x32); v12 1931 (2/SIMD 32x32x16); v13 2264
//  (16-wave 2-buf drain -- protocol, not occupancy, was at fault).]

#define NN 2048
#define PP 256
#define DT_C 0.1f
#define ON_TIME_C 10

typedef __attribute__((ext_vector_type(8)))  short bf16x8;
typedef __attribute__((ext_vector_type(16))) float f32x16;

__device__ __forceinline__ unsigned short bf16rne(float f) {
    unsigned b = __float_as_uint(f);
    return (unsigned short)((b + 0x7FFFu + ((b >> 16) & 1u)) >> 16);
}
// 32x32x16 fragment permutation within a 16-k group (v12-verified).
__device__ __forceinline__ int kperm16(int s) {
    return (s & 3) + (((s >> 2) & 1) << 3) + ((s >> 3) << 2);
}

// ---- J f32 [N][N] -> bf16 [N][N], k-permuted per 16-group ----
__global__ void convert_J_kernel(const float* __restrict__ J,
                                 unsigned short* __restrict__ Jp) {
    int i = blockIdx.x * blockDim.x + threadIdx.x;   // grid covers NN*NN
    int row = i >> 11, k = i & 2047;
    Jp[((size_t)row << 11) + (k & ~15) + kperm16(k & 15)] = bf16rne(J[i]);
}

// ---- x = 0, rates_T = bf16(0.5) (perm-invariant), out = 0 ----
__global__ void init_kernel(float* __restrict__ x,
                            unsigned short* __restrict__ rT,
                            float* __restrict__ out, int nout) {
    int i = blockIdx.x * blockDim.x + threadIdx.x;   // grid covers NN*PP
    x[i] = 0.0f;
    rT[i] = 0x3F00;
    if (i < nout) out[i] = 0.0f;
}

#define AS1 __attribute__((address_space(1)))
#define AS3 __attribute__((address_space(3)))
#define GLOAD16(g, l) \
    __builtin_amdgcn_global_load_lds((const AS1 void*)(g), (AS3 void*)(l), 16, 0, 0)

// ---- One time step. grid 256 (1/CU), 1024 thr (16 waves, 4/SIMD).
// BM=64 BN=32 BK=128, 16 phases, 4-buf LDS (4 x 24KB). ----
__global__ __launch_bounds__(1024, 1) void gemm_step_kernel(
    const unsigned short* __restrict__ Jp,    // [N][N] bf16 kperm16'd
    const unsigned short* __restrict__ rin,   // rates_T [P][N] bf16 kperm16'd
    unsigned short* __restrict__ rout,        // rates_T [P][N]
    float* __restrict__ x, const float* __restrict__ patterns,
    const float* __restrict__ w_out, float* __restrict__ out,
    int t, int T, int with_input) {

    __shared__ char smem[98304];              // 4 bufs x (A 16KB + B 8KB)

    const int tid  = threadIdx.x;
    const int wv   = tid >> 6;                // wave 0..15
    const int lane = tid & 63;
    const int s    = wv >> 3;                 // m-half (32 rows)
    const int kq   = wv & 7;                  // k-eighth role
    const int h    = lane >> 5;               // chunk-half within k16 frag

    // XCD-contiguous swizzle: XCD owns 4 contiguous m-panels.
    const int bid   = (blockIdx.x & 7) * 32 + (blockIdx.x >> 3);
    const int mbase = (bid >> 3) * 64;
    const int nbase = (bid & 7) * 32;

    // ---- staging: rows are 256B (16 chunks). Wave wv stages A rows
    // 4wv..4wv+3; waves 8..15 also stage B rows 4(wv-8)..4(wv-8)+3.
    // dest check: (tid>>4)*256 + (tid&15)*16 == 1024*wv + lane*16. ----
    const int sr = tid >> 4;                  // A staging row 0..63
    const int sp = tid & 15;                  // chunk
    const char* gA = (const char*)Jp + (((size_t)(mbase + sr)) << 12)
                     + ((sp ^ (sr & 15)) << 4);
    const int  ldsA = 1024 * wv;              // wave-uniform dest base
    const bool hasB = (wv >= 8);
    const int  rb   = sr - 32;                // B staging row 0..31 (w>=8)
    const char* gB = (const char*)rin + (((size_t)(nbase + (hasB ? rb : 0))) << 12)
                     + ((sp ^ (rb & 15)) << 4);
    const int  ldsB = 16384 + 1024 * (wv - 8);

    // ---- fragment read rows ----
    const int rA  = 32 * s + (lane & 31);     // A row (local, 0..63)
    const int rBn = lane & 31;                // B row (local n, 0..31)

    f32x16 acc = {};

    // prologue: stage phases 0,1 (per-stage order: A then B)
    GLOAD16(gA,       smem + 0 * 24576 + ldsA);
    if (hasB) GLOAD16(gB,       smem + 0 * 24576 + ldsB);
    GLOAD16(gA + 256, smem + 1 * 24576 + ldsA);
    if (hasB) GLOAD16(gB + 256, smem + 1 * 24576 + ldsB);

    // ---- K-loop: 16 phases of BK=128; wave computes k16 slice kq ----
    #pragma unroll
    for (int ph = 0; ph < 16; ++ph) {
        if (ph < 14) {                        // issue stage(ph+2)
            const int bo = ((ph + 2) & 3) * 24576;
            GLOAD16(gA + (ph + 2) * 256, smem + bo + ldsA);
            if (hasB) GLOAD16(gB + (ph + 2) * 256, smem + bo + ldsB);
        }
        // counted wait: stage(ph) retired; stages ph+1, ph+2 stay in flight.
        if (wv < 8) {                         // 1 load/stage
            if (ph < 14)       asm volatile("s_waitcnt vmcnt(2)" ::: "memory");
            else if (ph == 14) asm volatile("s_waitcnt vmcnt(1)" ::: "memory");
            else               asm volatile("s_waitcnt vmcnt(0)" ::: "memory");
        } else {                              // 2 loads/stage
            if (ph < 14)       asm volatile("s_waitcnt vmcnt(4)" ::: "memory");
            else if (ph == 14) asm volatile("s_waitcnt vmcnt(2)" ::: "memory");
            else               asm volatile("s_waitcnt vmcnt(0)" ::: "memory");
        }
        __builtin_amdgcn_s_barrier();         // all waves' stage(ph) visible
        __builtin_amdgcn_sched_barrier(0);    // keep reads below barrier

        const int bb = (ph & 3) * 24576;
        const int c  = kq * 2 + h;            // 16B chunk in 256B row
        bf16x8 a = *(const bf16x8*)(smem + bb + rA * 256
                                    + ((c ^ (rA & 15)) << 4));
        bf16x8 b = *(const bf16x8*)(smem + bb + 16384 + rBn * 256
                                    + ((c ^ (rBn & 15)) << 4));
        acc = __builtin_amdgcn_mfma_f32_32x32x16_bf16(a, b, acc, 0, 0, 0);
    }

    __syncthreads();                          // all reads done; reuse smem

    // ---- write kq-partials: plane (s*8+kq), [32 row][32 col] f32 = 64KB ----
    {
        float* pf = (float*)smem;
        const int plane = (s * 8 + kq) * 1024;
        #pragma unroll
        for (int reg = 0; reg < 16; ++reg) {
            int row = (reg & 3) + 8 * (reg >> 2) + 4 * h;   // v12-verified
            pf[plane + row * 32 + (lane & 31)] = acc[reg];
        }
    }
    __syncthreads();

    // ---- reduce 8 kq-planes + epilogue. thread -> (mloc, 2 cols) ----
    {
        const int mloc = tid >> 4;            // 0..63
        const int c2   = (tid & 15) * 2;      // 0..30
        const int s2   = mloc >> 5;
        const float* pf = (const float*)smem;
        float2 sum = make_float2(0.f, 0.f);
        #pragma unroll
        for (int q = 0; q < 8; ++q) {         // kq ascending: deterministic
            float2 v = *(const float2*)(pf + (s2 * 8 + q) * 1024
                                        + (mloc & 31) * 32 + c2);
            sum.x += v.x; sum.y += v.y;
        }

        const int m  = mbase + mloc;
        const int n0 = nbase + c2;
        size_t xo = ((size_t)m << 8) + n0;
        float2 xv = *(const float2*)(x + xo);
        float2 pv = make_float2(0.f, 0.f);
        if (with_input) pv = *(const float2*)(patterns + xo);
        float wsc = (w_out[m] != 0.0f) ? (1.0f / (float)NN) : 0.0f;

        float xn0 = xv.x + DT_C * (sum.x + pv.x - xv.x);
        float xn1 = xv.y + DT_C * (sum.y + pv.y - xv.y);
        *(float2*)(x + xo) = make_float2(xn0, xn1);
        float r0f = 0.5f * (1.0f + tanhf(xn0));
        float r1f = 0.5f * (1.0f + tanhf(xn1));
        if (wsc != 0.0f) {
            atomicAdd(&out[(size_t)n0 * T + t],       r0f * wsc);
            atomicAdd(&out[(size_t)(n0 + 1) * T + t], r1f * wsc);
        }
        // slab [32 n][64 m] bf16 at 65536, XOR-swizzled chunks (verified)
        const int pos = (mloc & ~15) + kperm16(mloc & 15);
        int b0 = 65536 + c2 * 128       + (((pos >> 3) ^ (c2 & 7)) << 4)       + (pos & 7) * 2;
        int b1 = 65536 + (c2 + 1) * 128 + (((pos >> 3) ^ ((c2 + 1) & 7)) << 4) + (pos & 7) * 2;
        *(unsigned short*)(smem + b0) = bf16rne(r0f);
        *(unsigned short*)(smem + b1) = bf16rne(r1f);
    }
    __syncthreads();
    if (tid < 256) {   // linear write-out of the block's [32 n][64 m] slab
        int nl = tid >> 3, pc = tid & 7;
        uint4 v = *(const uint4*)(smem + 65536 + nl * 128 + ((pc ^ (nl & 7)) << 4));
        *(uint4*)((char*)rout + (((size_t)(nbase + nl)) << 12) + mbase * 2 + pc * 16) = v;
    }
}

extern "C" void kernel_launch(void* const* d_in, const int* in_sizes, int n_in,
                              void* d_out, int out_size, void* d_ws, size_t ws_size,
                              hipStream_t stream) {
    const float* patterns = (const float*)d_in[0];   // [N, P]
    const float* J        = (const float*)d_in[1];   // [N, N]
    const float* w_out    = (const float*)d_in[2];   // [N]
    float* out            = (float*)d_out;           // [P, T]

    int T = out_size / PP;                           // 200

    size_t off = 0;
    auto alloc = [&](size_t bytes) {
        void* p = (char*)d_ws + off;
        off += (bytes + 255) & ~(size_t)255;
        return p;
    };
    unsigned short* Jp = (unsigned short*)alloc((size_t)NN * NN * 2);  // 8MB
    unsigned short* r0 = (unsigned short*)alloc((size_t)PP * NN * 2);  // 1MB
    unsigned short* r1 = (unsigned short*)alloc((size_t)PP * NN * 2);  // 1MB
    float*          x  = (float*)         alloc((size_t)NN * PP * 4);  // 2MB
    (void)ws_size; (void)n_in; (void)in_sizes;

    convert_J_kernel<<<(NN * NN) / 256, 256, 0, stream>>>(J, Jp);
    init_kernel<<<(NN * PP) / 256, 256, 0, stream>>>(x, r0, out, PP * T);

    for (int t = 0; t < T; ++t) {
        const unsigned short* rin = (t & 1) ? r1 : r0;
        unsigned short*      rout = (t & 1) ? r0 : r1;
        gemm_step_kernel<<<256, 1024, 0, stream>>>(Jp, rin, rout, x, patterns,
                                                   w_out, out, t, T,
                                                   (t < ON_TIME_C) ? 1 : 0);
    }
}

// Round 15
// 1942.103 us; speedup vs baseline: 1.1662x; 1.0206x over previous
//
#include <hip/hip_runtime.h>
#include <hip/hip_bf16.h>

// SRNN: x_{t+1} = x + DT*(-x + J@rates + inp), rates = 0.5*(1+tanh(x)),
// out[p,t] = (w_out @ rates_t)[p] / N.
//
// v15 = v12 (best, 1931us) with DEEPER STAGING PIPELINE only:
//  - 6 LDS bufs (144KB, was 4x24KB=96KB), prologue stages 4 phases,
//    issue stage(ph+4) per iter, steady vmcnt(12) -> 96KB/CU in flight
//    (was 48KB, marginal vs Little's-law need of ~39KB at ~700cy L2 lat).
//  - WAR proof: stage(ph+4)->buf[(ph-2)%6]; its readers ran in iter ph-2
//    before barrier(ph-1), which the issuer passed. Completion-time writes
//    therefore race-free.
//  - epilogue operands (x/patterns/w_out) prefetched at kernel top; vmcnt
//    constants remain sufficient under any load-issue interleaving.
//  - occupancy ruled out by v14 (4 w/SIMD == 2 w/SIMD); protocol drain
//    ruled out by v13 (vmcnt(0)/phase = +330us).
// [history: sparse 2114-2360; coop/persistent dead ends; v9 2119 (1w/SIMD);
//  v10 1972; v12 1931 (2w/SIMD 32x32x16); v13 2264; v14 1982 (4w/SIMD).]

#define NN 2048
#define PP 256
#define DT_C 0.1f
#define ON_TIME_C 10

typedef __attribute__((ext_vector_type(8)))  short bf16x8;
typedef __attribute__((ext_vector_type(16))) float f32x16;

__device__ __forceinline__ unsigned short bf16rne(float f) {
    unsigned b = __float_as_uint(f);
    return (unsigned short)((b + 0x7FFFu + ((b >> 16) & 1u)) >> 16);
}
// 32x32x16 fragment permutation within a 16-k group (v12-verified).
__device__ __forceinline__ int kperm16(int s) {
    return (s & 3) + (((s >> 2) & 1) << 3) + ((s >> 3) << 2);
}

// ---- J f32 [N][N] -> bf16 [N][N], k-permuted per 16-group ----
__global__ void convert_J_kernel(const float* __restrict__ J,
                                 unsigned short* __restrict__ Jp) {
    int i = blockIdx.x * blockDim.x + threadIdx.x;   // grid covers NN*NN
    int row = i >> 11, k = i & 2047;
    Jp[((size_t)row << 11) + (k & ~15) + kperm16(k & 15)] = bf16rne(J[i]);
}

// ---- x = 0, rates_T = bf16(0.5) (perm-invariant), out = 0 ----
__global__ void init_kernel(float* __restrict__ x,
                            unsigned short* __restrict__ rT,
                            float* __restrict__ out, int nout) {
    int i = blockIdx.x * blockDim.x + threadIdx.x;   // grid covers NN*PP
    x[i] = 0.0f;
    rT[i] = 0x3F00;
    if (i < nout) out[i] = 0.0f;
}

#define AS1 __attribute__((address_space(1)))
#define AS3 __attribute__((address_space(3)))
#define GLOAD16(g, l) \
    __builtin_amdgcn_global_load_lds((const AS1 void*)(g), (AS3 void*)(l), 16, 0, 0)

// ---- One time step. grid 256 (1/CU), 512 thr (8 waves).
// BM=64 BN=32 BK=128, 16 phases, 6-buf LDS (6 x 24KB = 144KB). ----
__global__ __launch_bounds__(512, 1) void gemm_step_kernel(
    const unsigned short* __restrict__ Jp,    // [N][N] bf16 kperm16'd
    const unsigned short* __restrict__ rin,   // rates_T [P][N] bf16 kperm16'd
    unsigned short* __restrict__ rout,        // rates_T [P][N]
    float* __restrict__ x, const float* __restrict__ patterns,
    const float* __restrict__ w_out, float* __restrict__ out,
    int t, int T, int with_input) {

    __shared__ char smem[147456];             // 6 bufs x (A 16KB + B 8KB)

    const int tid  = threadIdx.x;
    const int w    = tid >> 6;                // wave 0..7
    const int lane = tid & 63;
    const int s    = w >> 2;                  // m-half (32 rows)
    const int kq   = w & 3;                   // K-quarter role
    const int h    = lane >> 5;               // chunk-half within k16 frag

    // XCD-contiguous swizzle: XCD owns 4 contiguous m-panels.
    const int bid   = (blockIdx.x & 7) * 32 + (blockIdx.x >> 3);
    const int mbase = (bid >> 3) * 64;
    const int nbase = (bid & 7) * 32;

    // ---- staging (v12): wave stages A rows 8w..8w+7 (2 loads), B rows
    // 4w..4w+3 (1 load); 3 loads/wave/stage, 24 loads/block/stage. ----
    const int rA0 = 8 * w + (lane >> 4);
    const int rA1 = rA0 + 4;
    const int rB  = 4 * w + (lane >> 4);
    const char* gA0 = (const char*)Jp  + (((size_t)(mbase + rA0)) << 12)
                      + (((lane & 15) ^ (rA0 & 15)) << 4);
    const char* gA1 = (const char*)Jp  + (((size_t)(mbase + rA1)) << 12)
                      + (((lane & 15) ^ (rA1 & 15)) << 4);
    const char* gB  = (const char*)rin + (((size_t)(nbase + rB )) << 12)
                      + (((lane & 15) ^ (rB  & 15)) << 4);
    const int ldsA0 = (8 * w) * 256, ldsA1 = (8 * w + 4) * 256;
    const int ldsB  = 16384 + 4 * w * 256;

    // ---- fragment read rows ----
    const int rA  = 32 * s + (lane & 31);     // A row (local, 0..63)
    const int rBn = lane & 31;                // B row (local n, 0..31)

    // ---- epilogue operand PREFETCH (retires under early vmcnt waits;
    // vmcnt constants below remain sufficient under any interleaving) ----
    const int e_s2 = tid >> 8, e_rr = (tid >> 3) & 31, e_c4 = (tid & 7) * 4;
    const int e_mloc = e_s2 * 32 + e_rr;
    const int e_m  = mbase + e_mloc;
    const int e_n0 = nbase + e_c4;
    const size_t e_xo = ((size_t)e_m << 8) + e_n0;
    float4 e_xv = *(const float4*)(x + e_xo);
    float4 e_pv = make_float4(0.f, 0.f, 0.f, 0.f);
    if (with_input) e_pv = *(const float4*)(patterns + e_xo);
    float e_wsc = (w_out[e_m] != 0.0f) ? (1.0f / (float)NN) : 0.0f;

    f32x16 acc = {};

    // prologue: stage phases 0..3
    #pragma unroll
    for (int ps = 0; ps < 4; ++ps) {
        GLOAD16(gA0 + ps * 256, smem + ps * 24576 + ldsA0);
        GLOAD16(gA1 + ps * 256, smem + ps * 24576 + ldsA1);
        GLOAD16(gB  + ps * 256, smem + ps * 24576 + ldsB);
    }

    // ---- K-loop: 16 phases of BK=128; wave computes k16 slices 2kq,2kq+1 ----
    #pragma unroll
    for (int ph = 0; ph < 16; ++ph) {
        if (ph < 12) {                        // issue stage(ph+4)
            const int bo = ((ph + 4) % 6) * 24576;
            GLOAD16(gA0 + (ph + 4) * 256, smem + bo + ldsA0);
            GLOAD16(gA1 + (ph + 4) * 256, smem + bo + ldsA1);
            GLOAD16(gB  + (ph + 4) * 256, smem + bo + ldsB);
        }
        // counted wait: stage(ph) retired; up to 4 stages stay in flight.
        if (ph < 12)       asm volatile("s_waitcnt vmcnt(12)" ::: "memory");
        else if (ph == 12) asm volatile("s_waitcnt vmcnt(9)"  ::: "memory");
        else if (ph == 13) asm volatile("s_waitcnt vmcnt(6)"  ::: "memory");
        else if (ph == 14) asm volatile("s_waitcnt vmcnt(3)"  ::: "memory");
        else               asm volatile("s_waitcnt vmcnt(0)"  ::: "memory");
        __builtin_amdgcn_s_barrier();         // all waves' stage(ph) visible
        __builtin_amdgcn_sched_barrier(0);    // keep reads below barrier

        const int bb = (ph % 6) * 24576;
        #pragma unroll
        for (int sl = 0; sl < 2; ++sl) {
            const int c = kq * 4 + sl * 2 + h;    // 16B chunk in 256B row
            bf16x8 a = *(const bf16x8*)(smem + bb + rA * 256
                                        + ((c ^ (rA & 15)) << 4));
            bf16x8 b = *(const bf16x8*)(smem + bb + 16384 + rBn * 256
                                        + ((c ^ (rBn & 15)) << 4));
            acc = __builtin_amdgcn_mfma_f32_32x32x16_bf16(a, b, acc, 0, 0, 0);
        }
    }

    __syncthreads();                          // all reads done; reuse smem

    // ---- write kq-partials: plane (s*4+kq), [32 row][32 col] f32 = 32KB ----
    {
        float* pf = (float*)smem;
        const int plane = (s * 4 + kq) * 1024;
        #pragma unroll
        for (int reg = 0; reg < 16; ++reg) {
            int row = (reg & 3) + 8 * (reg >> 2) + 4 * h;   // v12-verified
            pf[plane + row * 32 + (lane & 31)] = acc[reg];
        }
    }
    __syncthreads();

    // ---- reduce 4 kq-planes + epilogue (prefetched operands) ----
    {
        const float4* pf4 = (const float4*)smem;
        int base = ((e_s2 * 4) * 1024 + e_rr * 32 + e_c4) >> 2;  // float4 idx
        float4 v0 = pf4[base], v1 = pf4[base + 256];
        float4 v2 = pf4[base + 512], v3 = pf4[base + 768];
        float sum[4] = {v0.x + v1.x + v2.x + v3.x, v0.y + v1.y + v2.y + v3.y,
                        v0.z + v1.z + v2.z + v3.z, v0.w + v1.w + v2.w + v3.w};

        float xn[4] = {e_xv.x + DT_C * (sum[0] + e_pv.x - e_xv.x),
                       e_xv.y + DT_C * (sum[1] + e_pv.y - e_xv.y),
                       e_xv.z + DT_C * (sum[2] + e_pv.z - e_xv.z),
                       e_xv.w + DT_C * (sum[3] + e_pv.w - e_xv.w)};
        *(float4*)(x + e_xo) = make_float4(xn[0], xn[1], xn[2], xn[3]);

        const int pos = (e_mloc & ~15) + kperm16(e_mloc & 15);
        #pragma unroll
        for (int j = 0; j < 4; ++j) {
            float r = 0.5f * (1.0f + tanhf(xn[j]));
            if (e_wsc != 0.0f)
                atomicAdd(&out[(size_t)(e_n0 + j) * T + t], r * e_wsc);
            int nloc = e_c4 + j;
            int byte = 32768 + nloc * 128
                     + (((pos >> 3) ^ (nloc & 7)) << 4) + (pos & 7) * 2;
            *(unsigned short*)(smem + byte) = bf16rne(r);
        }
    }
    __syncthreads();
    if (tid < 256) {   // linear write-out of the block's [32 n][64 m] slab
        int nl = tid >> 3, pc = tid & 7;
        uint4 v = *(const uint4*)(smem + 32768 + nl * 128 + ((pc ^ (nl & 7)) << 4));
        *(uint4*)((char*)rout + (((size_t)(nbase + nl)) << 12) + mbase * 2 + pc * 16) = v;
    }
}

extern "C" void kernel_launch(void* const* d_in, const int* in_sizes, int n_in,
                              void* d_out, int out_size, void* d_ws, size_t ws_size,
                              hipStream_t stream) {
    const float* patterns = (const float*)d_in[0];   // [N, P]
    const float* J        = (const float*)d_in[1];   // [N, N]
    const float* w_out    = (const float*)d_in[2];   // [N]
    float* out            = (float*)d_out;           // [P, T]

    int T = out_size / PP;                           // 200

    size_t off = 0;
    auto alloc = [&](size_t bytes) {
        void* p = (char*)d_ws + off;
        off += (bytes + 255) & ~(size_t)255;
        return p;
    };
    unsigned short* Jp = (unsigned short*)alloc((size_t)NN * NN * 2);  // 8MB
    unsigned short* r0 = (unsigned short*)alloc((size_t)PP * NN * 2);  // 1MB
    unsigned short* r1 = (unsigned short*)alloc((size_t)PP * NN * 2);  // 1MB
    float*          x  = (float*)         alloc((size_t)NN * PP * 4);  // 2MB
    (void)ws_size; (void)n_in; (void)in_sizes;

    convert_J_kernel<<<(NN * NN) / 256, 256, 0, stream>>>(J, Jp);
    init_kernel<<<(NN * PP) / 256, 256, 0, stream>>>(x, r0, out, PP * T);

    for (int t = 0; t < T; ++t) {
        const unsigned short* rin = (t & 1) ? r1 : r0;
        unsigned short*      rout = (t & 1) ? r0 : r1;
        gemm_step_kernel<<<256, 512, 0, stream>>>(Jp, rin, rout, x, patterns,
                                                  w_out, out, t, T,
                                                  (t < ON_TIME_C) ? 1 : 0);
    }
}